// Round 6
// baseline (94.751 us; speedup 1.0000x reference)
//
#include <hip/hip_runtime.h>
#include <hip/hip_fp16.h>

// DistMult forward scoring: score[e] = sum_d h[src,d] * fwd_rel[et,d] * h[dst,d]
// E=640000, D=128, fp32 in/out.
//
// R10: occupancy experiment, minimal diff from R7 (last known-good).
// R7 accounting: main kernel ~45us = 7.3 TB/s from an L2-resident table,
// Occupancy 34% / VALUBusy 13% -> latency-starved at 4 waves/SIMD because
// the 128 KB LDS w-table caps 1 block/CU. This round: IDENTICAL launch
// geometry to R7 (256 blocks x 1024 threads, EPT=4, index prefetch,
// v_pk_mul_f16 + v_fma_mix_f32 dots) but NO LDS at all -- w rows gathered
// from global (128 KB fp16 table, hot in every XCD L2 / partly L1).
// LDS=0 -> blocks/CU set by VGPR only (~64 VGPR -> 2 blocks/CU = 8
// waves/SIMD, 2x R7's wave supply).
// Outcomes: faster -> occupancy was the limiter; slower -> L2 delivery
// throughput is the wall (w traffic +50%) -> revert to R7, declare roofline.

typedef unsigned short u16;
typedef _Float16 h2v __attribute__((ext_vector_type(2)));

constexpr int EMB_DIM  = 128;
constexpr int BLOCKS   = 256;    // 1 per CU
constexpr int THREADS  = 1024;   // 64 teams of 16 lanes

// ---- fp32 -> fp16 pack, 8 floats per slot ----
__device__ __forceinline__ void convert_slot(const float* __restrict__ s,
                                             u16* __restrict__ d, int j) {
    float4 lo = reinterpret_cast<const float4*>(s)[j * 2];
    float4 hi = reinterpret_cast<const float4*>(s)[j * 2 + 1];
    u16 u0 = __half_as_ushort(__float2half(lo.x));
    u16 u1 = __half_as_ushort(__float2half(lo.y));
    u16 u2 = __half_as_ushort(__float2half(lo.z));
    u16 u3 = __half_as_ushort(__float2half(lo.w));
    u16 u4 = __half_as_ushort(__float2half(hi.x));
    u16 u5 = __half_as_ushort(__float2half(hi.y));
    u16 u6 = __half_as_ushort(__float2half(hi.z));
    u16 u7 = __half_as_ushort(__float2half(hi.w));
    uint4 v;
    v.x = (unsigned)u0 | ((unsigned)u1 << 16);
    v.y = (unsigned)u2 | ((unsigned)u3 << 16);
    v.z = (unsigned)u4 | ((unsigned)u5 << 16);
    v.w = (unsigned)u6 | ((unsigned)u7 << 16);
    reinterpret_cast<uint4*>(d)[j] = v;
}

__global__ __launch_bounds__(256) void convert_fp16_kernel(
    const float* __restrict__ a, u16* __restrict__ a16, int n_a8,
    const float* __restrict__ b, u16* __restrict__ b16, int n_b8)
{
    const int total = n_a8 + n_b8;
    for (int i = blockIdx.x * blockDim.x + threadIdx.x; i < total;
         i += gridDim.x * blockDim.x) {
        if (i < n_a8) convert_slot(a, a16, i);
        else          convert_slot(b, b16, i - n_a8);
    }
}

// 8-element triple product, f32 accumulate.
// t = a*c packed fp16 (v_pk_mul_f16); (float)t * (float)b + acc folds to
// v_fma_mix_f32. ~12 VALU per dot8.
__device__ __forceinline__ float dot8(uint4 A, uint4 B, uint4 C) {
    const h2v* a = reinterpret_cast<const h2v*>(&A);
    const h2v* b = reinterpret_cast<const h2v*>(&B);
    const h2v* c = reinterpret_cast<const h2v*>(&C);
    float acc = 0.f;
    #pragma unroll
    for (int k = 0; k < 4; ++k) {
        h2v t = a[k] * c[k];                    // v_pk_mul_f16
        acc += (float)t.x * (float)b[k].x;      // v_fma_mix_f32
        acc += (float)t.y * (float)b[k].y;      // v_fma_mix_f32
    }
    return acc;
}

__device__ __forceinline__ float team_reduce16(float acc) {
    #pragma unroll
    for (int off = 8; off > 0; off >>= 1)
        acc += __shfl_down(acc, off, 16);
    return acc;
}

__global__ __launch_bounds__(THREADS) void distmult_fp16_kernel(
    const u16* __restrict__ h16,     // [n_nodes][128] fp16
    const int* __restrict__ src,
    const int* __restrict__ dst,
    const int* __restrict__ etype,
    const u16* __restrict__ w16,     // [n_rels][128] fp16
    float*     __restrict__ out,
    int n_edges)
{
    const int team = threadIdx.x >> 4;   // 64 teams
    const int lane = threadIdx.x & 15;

    const uint4* hp = reinterpret_cast<const uint4*>(h16) + lane;  // +16/row
    const uint4* wp = reinterpret_cast<const uint4*>(w16) + lane;

    const int stride = BLOCKS * (THREADS / 16) * 4;   // 65536 edges/pass

    int e0 = (blockIdx.x * (THREADS / 16) + team) * 4;
    int4 s4, d4, t4;
    bool valid = (e0 + 3 < n_edges);
    if (valid) {
        s4 = *reinterpret_cast<const int4*>(src   + e0);
        d4 = *reinterpret_cast<const int4*>(dst   + e0);
        t4 = *reinterpret_cast<const int4*>(etype + e0);
    }

    while (valid) {
        // prefetch next iteration's indices: takes the cold HBM index read
        // off the critical chain (hides under the 12 gathers + compute)
        const int e1 = e0 + stride;
        const bool nvalid = (e1 + 3 < n_edges);
        int4 ns = s4, nd = d4, nt = t4;
        if (nvalid) {
            ns = *reinterpret_cast<const int4*>(src   + e1);
            nd = *reinterpret_cast<const int4*>(dst   + e1);
            nt = *reinterpret_cast<const int4*>(etype + e1);
        }

        // 12 L2 gathers in flight: full 256 B fp16 rows, 16 B/lane
        const uint4 a0 = hp[(size_t)(unsigned)s4.x * 16];
        const uint4 a1 = hp[(size_t)(unsigned)s4.y * 16];
        const uint4 a2 = hp[(size_t)(unsigned)s4.z * 16];
        const uint4 a3 = hp[(size_t)(unsigned)s4.w * 16];
        const uint4 c0 = hp[(size_t)(unsigned)d4.x * 16];
        const uint4 c1 = hp[(size_t)(unsigned)d4.y * 16];
        const uint4 c2 = hp[(size_t)(unsigned)d4.z * 16];
        const uint4 c3 = hp[(size_t)(unsigned)d4.w * 16];
        const uint4 b0 = wp[(size_t)(unsigned)t4.x * 16];
        const uint4 b1 = wp[(size_t)(unsigned)t4.y * 16];
        const uint4 b2 = wp[(size_t)(unsigned)t4.z * 16];
        const uint4 b3 = wp[(size_t)(unsigned)t4.w * 16];

        float acc0 = dot8(a0, b0, c0);
        float acc1 = dot8(a1, b1, c1);
        float acc2 = dot8(a2, b2, c2);
        float acc3 = dot8(a3, b3, c3);

        acc0 = team_reduce16(acc0);
        acc1 = team_reduce16(acc1);
        acc2 = team_reduce16(acc2);
        acc3 = team_reduce16(acc3);

        if (lane == 0)
            *reinterpret_cast<float4*>(out + e0) =
                make_float4(acc0, acc1, acc2, acc3);

        e0 = e1; s4 = ns; d4 = nd; t4 = nt; valid = nvalid;
    }

    // tail: fewer than 4 edges left for this team
    for (int e = e0; e < n_edges && e < e0 + 4; ++e) {
        const uint4 a = hp[(size_t)(unsigned)src[e]   * 16];
        const uint4 c = hp[(size_t)(unsigned)dst[e]   * 16];
        const uint4 b = wp[(size_t)(unsigned)etype[e] * 16];
        float acc = team_reduce16(dot8(a, b, c));
        if (lane == 0) out[e] = acc;
    }
}

// fallback: fp32 direct if ws too small
__global__ __launch_bounds__(256) void distmult_score_kernel(
    const float* __restrict__ h,
    const int*   __restrict__ src,
    const int*   __restrict__ dst,
    const int*   __restrict__ etype,
    const float* __restrict__ fwd_rel,
    float*       __restrict__ out,
    int n_edges)
{
    const int tid  = blockIdx.x * blockDim.x + threadIdx.x;
    const int lane = threadIdx.x & 63;
    const int half = lane >> 5;
    const int sub  = lane & 31;
    const int edge = (tid >> 6) * 2 + half;
    if (edge >= n_edges) return;

    const int s = src[edge];
    const int d = dst[edge];
    const int e = etype[edge];

    const float4 a = reinterpret_cast<const float4*>(h       + (size_t)s * EMB_DIM)[sub];
    const float4 b = reinterpret_cast<const float4*>(fwd_rel + (size_t)e * EMB_DIM)[sub];
    const float4 c = reinterpret_cast<const float4*>(h       + (size_t)d * EMB_DIM)[sub];

    float acc = a.x*b.x*c.x + a.y*b.y*c.y + a.z*b.z*c.z + a.w*b.w*c.w;
    #pragma unroll
    for (int off = 16; off > 0; off >>= 1)
        acc += __shfl_down(acc, off, 32);
    if (sub == 0) out[edge] = acc;
}

extern "C" void kernel_launch(void* const* d_in, const int* in_sizes, int n_in,
                              void* d_out, int out_size, void* d_ws, size_t ws_size,
                              hipStream_t stream) {
    const float* h       = (const float*)d_in[0];
    const int*   src     = (const int*)d_in[1];
    const int*   dst     = (const int*)d_in[2];
    const int*   etype   = (const int*)d_in[3];
    const float* fwd_rel = (const float*)d_in[4];
    float* out = (float*)d_out;

    const int n_edges = in_sizes[1];
    const int n_h     = in_sizes[0];              // n_nodes*128
    const int n_w     = in_sizes[4];              // n_rels*128
    const size_t need = (size_t)(n_h + n_w) * sizeof(u16);

    if (ws_size >= need && (n_h % 8) == 0 && (n_w % 8) == 0) {
        u16* h16 = (u16*)d_ws;
        u16* w16 = h16 + n_h;

        const int n_a8 = n_h / 8, n_b8 = n_w / 8;
        const int cgrid = (n_a8 + n_b8 + 255) / 256;
        convert_fp16_kernel<<<cgrid, 256, 0, stream>>>(
            h, h16, n_a8, fwd_rel, w16, n_b8);

        distmult_fp16_kernel<<<BLOCKS, THREADS, 0, stream>>>(
            h16, src, dst, etype, w16, out, n_edges);
    } else {
        const int grid = (n_edges + 7) / 8;
        distmult_score_kernel<<<grid, 256, 0, stream>>>(
            h, src, dst, etype, fwd_rel, out, n_edges);
    }
}

// Round 7
// 91.709 us; speedup vs baseline: 1.0332x; 1.0332x over previous
//
#include <hip/hip_runtime.h>
#include <hip/hip_fp16.h>

// DistMult forward scoring: score[e] = sum_d h[src,d] * fwd_rel[et,d] * h[dst,d]
// E=640000, D=128, fp32 in/out.
//
// R11 = R7 verbatim (best measured: 91.9us). Terminal revert after the
// R10 occupancy experiment refuted the occupancy hypothesis (no-LDS,
// 2x waves/SIMD -> 94.8us, slightly WORSE). Evidence across rounds:
//   R6 : 2x ILP -> VGPR spill (FETCH 83MB/WRITE 115MB scratch), worse.
//   R10: 2x occupancy -> no gain; w-gathers from L2 marginally worse
//        than LDS-staged w.
//   R5 : main-kernel HBM ~5%, VALUBusy ~15%, 0 bank conflicts.
// Conclusion: main kernel (~24-27us by cross-round accounting) is bound by
// L2 random-row gather service throughput (~13 TB/s effective for 2x256B
// rows/edge from the L2-resident fp16 h table). Total floor: ~42.6us
// harness ws-poison fill + ~20us fixed dispatch overhead + ~3us convert +
// ~24us L2-bound main ~= 90us; this kernel measures 91.9.
//
// Structure: fp16 h table in ws (2.56 MB, L2-resident per XCD), fp16
// fwd_rel staged in 128 KB LDS, 16-lane teams gather full 256B rows at
// 16B/lane, EPT=4 (8 row-gathers in flight), next-iter index prefetch,
// v_pk_mul_f16 + v_fma_mix_f32 dot math, width-16 shuffle reduce.

typedef unsigned short u16;
typedef _Float16 h2v __attribute__((ext_vector_type(2)));

constexpr int EMB_DIM  = 128;
constexpr int MAX_RELS = 500;
constexpr int BLOCKS   = 256;    // 1 per CU
constexpr int THREADS  = 1024;   // 64 teams of 16 lanes

// ---- fp32 -> fp16 pack, 8 floats per slot ----
__device__ __forceinline__ void convert_slot(const float* __restrict__ s,
                                             u16* __restrict__ d, int j) {
    float4 lo = reinterpret_cast<const float4*>(s)[j * 2];
    float4 hi = reinterpret_cast<const float4*>(s)[j * 2 + 1];
    u16 u0 = __half_as_ushort(__float2half(lo.x));
    u16 u1 = __half_as_ushort(__float2half(lo.y));
    u16 u2 = __half_as_ushort(__float2half(lo.z));
    u16 u3 = __half_as_ushort(__float2half(lo.w));
    u16 u4 = __half_as_ushort(__float2half(hi.x));
    u16 u5 = __half_as_ushort(__float2half(hi.y));
    u16 u6 = __half_as_ushort(__float2half(hi.z));
    u16 u7 = __half_as_ushort(__float2half(hi.w));
    uint4 v;
    v.x = (unsigned)u0 | ((unsigned)u1 << 16);
    v.y = (unsigned)u2 | ((unsigned)u3 << 16);
    v.z = (unsigned)u4 | ((unsigned)u5 << 16);
    v.w = (unsigned)u6 | ((unsigned)u7 << 16);
    reinterpret_cast<uint4*>(d)[j] = v;
}

__global__ __launch_bounds__(256) void convert_fp16_kernel(
    const float* __restrict__ a, u16* __restrict__ a16, int n_a8,
    const float* __restrict__ b, u16* __restrict__ b16, int n_b8)
{
    const int total = n_a8 + n_b8;
    for (int i = blockIdx.x * blockDim.x + threadIdx.x; i < total;
         i += gridDim.x * blockDim.x) {
        if (i < n_a8) convert_slot(a, a16, i);
        else          convert_slot(b, b16, i - n_a8);
    }
}

// 8-element triple product, f32 accumulate.
// t = a*c packed fp16 (v_pk_mul_f16); (float)t * (float)b + acc folds to
// v_fma_mix_f32. ~12 VALU per dot8.
__device__ __forceinline__ float dot8(uint4 A, uint4 B, uint4 C) {
    const h2v* a = reinterpret_cast<const h2v*>(&A);
    const h2v* b = reinterpret_cast<const h2v*>(&B);
    const h2v* c = reinterpret_cast<const h2v*>(&C);
    float acc = 0.f;
    #pragma unroll
    for (int k = 0; k < 4; ++k) {
        h2v t = a[k] * c[k];                    // v_pk_mul_f16
        acc += (float)t.x * (float)b[k].x;      // v_fma_mix_f32
        acc += (float)t.y * (float)b[k].y;      // v_fma_mix_f32
    }
    return acc;
}

__device__ __forceinline__ float team_reduce16(float acc) {
    #pragma unroll
    for (int off = 8; off > 0; off >>= 1)
        acc += __shfl_down(acc, off, 16);
    return acc;
}

__global__ __launch_bounds__(THREADS) void distmult_fp16_kernel(
    const u16* __restrict__ h16,     // [n_nodes][128] fp16
    const int* __restrict__ src,
    const int* __restrict__ dst,
    const int* __restrict__ etype,
    const u16* __restrict__ w16,     // [n_rels][128] fp16
    float*     __restrict__ out,
    int n_edges, int n_rels)
{
    __shared__ u16 w_lds[MAX_RELS * EMB_DIM];   // 128 KB

    // stage fwd_rel fp16 into LDS (linear, coalesced uint4)
    {
        const int slots = n_rels * (EMB_DIM / 8);
        for (int s = threadIdx.x; s < slots; s += THREADS)
            reinterpret_cast<uint4*>(w_lds)[s] =
                reinterpret_cast<const uint4*>(w16)[s];
    }
    __syncthreads();

    const int team = threadIdx.x >> 4;   // 64 teams
    const int lane = threadIdx.x & 15;

    const uint4* hp = reinterpret_cast<const uint4*>(h16) + lane;  // +16/row
    const uint4* wl = reinterpret_cast<const uint4*>(w_lds) + lane;

    const int stride = BLOCKS * (THREADS / 16) * 4;   // 65536 edges/pass

    int e0 = (blockIdx.x * (THREADS / 16) + team) * 4;
    int4 s4, d4, t4;
    bool valid = (e0 + 3 < n_edges);
    if (valid) {
        s4 = *reinterpret_cast<const int4*>(src   + e0);
        d4 = *reinterpret_cast<const int4*>(dst   + e0);
        t4 = *reinterpret_cast<const int4*>(etype + e0);
    }

    while (valid) {
        // prefetch next iteration's indices: takes the cold HBM index read
        // off the critical chain (hides under the 8 gathers + compute)
        const int e1 = e0 + stride;
        const bool nvalid = (e1 + 3 < n_edges);
        int4 ns = s4, nd = d4, nt = t4;
        if (nvalid) {
            ns = *reinterpret_cast<const int4*>(src   + e1);
            nd = *reinterpret_cast<const int4*>(dst   + e1);
            nt = *reinterpret_cast<const int4*>(etype + e1);
        }

        // 8 L2 gathers in flight: full 256 B fp16 rows, 16 B/lane
        const uint4 a0 = hp[(size_t)(unsigned)s4.x * 16];
        const uint4 a1 = hp[(size_t)(unsigned)s4.y * 16];
        const uint4 a2 = hp[(size_t)(unsigned)s4.z * 16];
        const uint4 a3 = hp[(size_t)(unsigned)s4.w * 16];
        const uint4 c0 = hp[(size_t)(unsigned)d4.x * 16];
        const uint4 c1 = hp[(size_t)(unsigned)d4.y * 16];
        const uint4 c2 = hp[(size_t)(unsigned)d4.z * 16];
        const uint4 c3 = hp[(size_t)(unsigned)d4.w * 16];
        // 4 LDS reads for w
        const uint4 b0 = wl[(unsigned)t4.x * 16];
        const uint4 b1 = wl[(unsigned)t4.y * 16];
        const uint4 b2 = wl[(unsigned)t4.z * 16];
        const uint4 b3 = wl[(unsigned)t4.w * 16];

        float acc0 = dot8(a0, b0, c0);
        float acc1 = dot8(a1, b1, c1);
        float acc2 = dot8(a2, b2, c2);
        float acc3 = dot8(a3, b3, c3);

        acc0 = team_reduce16(acc0);
        acc1 = team_reduce16(acc1);
        acc2 = team_reduce16(acc2);
        acc3 = team_reduce16(acc3);

        if (lane == 0)
            *reinterpret_cast<float4*>(out + e0) =
                make_float4(acc0, acc1, acc2, acc3);

        e0 = e1; s4 = ns; d4 = nd; t4 = nt; valid = nvalid;
    }

    // tail: fewer than 4 edges left for this team
    for (int e = e0; e < n_edges && e < e0 + 4; ++e) {
        const uint4 a = hp[(size_t)(unsigned)src[e]   * 16];
        const uint4 c = hp[(size_t)(unsigned)dst[e]   * 16];
        const uint4 b = wl[(unsigned)etype[e] * 16];
        float acc = team_reduce16(dot8(a, b, c));
        if (lane == 0) out[e] = acc;
    }
}

// fallback: fp32 direct if ws too small or n_rels > MAX_RELS
__global__ __launch_bounds__(256) void distmult_score_kernel(
    const float* __restrict__ h,
    const int*   __restrict__ src,
    const int*   __restrict__ dst,
    const int*   __restrict__ etype,
    const float* __restrict__ fwd_rel,
    float*       __restrict__ out,
    int n_edges)
{
    const int tid  = blockIdx.x * blockDim.x + threadIdx.x;
    const int lane = threadIdx.x & 63;
    const int half = lane >> 5;
    const int sub  = lane & 31;
    const int edge = (tid >> 6) * 2 + half;
    if (edge >= n_edges) return;

    const int s = src[edge];
    const int d = dst[edge];
    const int e = etype[edge];

    const float4 a = reinterpret_cast<const float4*>(h       + (size_t)s * EMB_DIM)[sub];
    const float4 b = reinterpret_cast<const float4*>(fwd_rel + (size_t)e * EMB_DIM)[sub];
    const float4 c = reinterpret_cast<const float4*>(h       + (size_t)d * EMB_DIM)[sub];

    float acc = a.x*b.x*c.x + a.y*b.y*c.y + a.z*b.z*c.z + a.w*b.w*c.w;
    #pragma unroll
    for (int off = 16; off > 0; off >>= 1)
        acc += __shfl_down(acc, off, 32);
    if (sub == 0) out[edge] = acc;
}

extern "C" void kernel_launch(void* const* d_in, const int* in_sizes, int n_in,
                              void* d_out, int out_size, void* d_ws, size_t ws_size,
                              hipStream_t stream) {
    const float* h       = (const float*)d_in[0];
    const int*   src     = (const int*)d_in[1];
    const int*   dst     = (const int*)d_in[2];
    const int*   etype   = (const int*)d_in[3];
    const float* fwd_rel = (const float*)d_in[4];
    float* out = (float*)d_out;

    const int n_edges = in_sizes[1];
    const int n_h     = in_sizes[0];              // n_nodes*128
    const int n_w     = in_sizes[4];              // n_rels*128
    const int n_rels  = n_w / EMB_DIM;
    const size_t need = (size_t)(n_h + n_w) * sizeof(u16);

    if (ws_size >= need && n_rels <= MAX_RELS &&
        (n_h % 8) == 0 && (n_w % 8) == 0) {
        u16* h16 = (u16*)d_ws;
        u16* w16 = h16 + n_h;

        const int n_a8 = n_h / 8, n_b8 = n_w / 8;
        const int cgrid = (n_a8 + n_b8 + 255) / 256;
        convert_fp16_kernel<<<cgrid, 256, 0, stream>>>(
            h, h16, n_a8, fwd_rel, w16, n_b8);

        distmult_fp16_kernel<<<BLOCKS, THREADS, 0, stream>>>(
            h16, src, dst, etype, w16, out, n_edges, n_rels);
    } else {
        const int grid = (n_edges + 7) / 8;
        distmult_score_kernel<<<grid, 256, 0, stream>>>(
            h, src, dst, etype, fwd_rel, out, n_edges);
    }
}